// Round 2
// 367.866 us; speedup vs baseline: 1.0419x; 1.0419x over previous
//
#include <hip/hip_runtime.h>

#define N_NODES 100000
#define N_EDGES 1600000

#define BKT_SHIFT 8
#define BKT_NODES 256
#define NBK ((N_NODES + BKT_NODES - 1) / BKT_NODES)      // 391 buckets
#define CHUNK 4096
#define NCHUNKS ((N_EDGES + CHUNK - 1) / CHUNK)          // 391 chunks
#define BCAP 6144                                        // LDS cap per bucket (avg 4096, ~32 sigma)

typedef _Float16 half8 __attribute__((ext_vector_type(8)));
typedef float floatx4 __attribute__((ext_vector_type(4)));

// ---------------- bucket-level histogram (391 bins) ----------------
__global__ __launch_bounds__(512) void bhist_kernel(const int* __restrict__ dst,
                                                    int* __restrict__ bhist) {
    __shared__ int h[NBK];
    for (int i = threadIdx.x; i < NBK; i += 512) h[i] = 0;
    __syncthreads();
    int stride = gridDim.x * 512;
    for (int e = blockIdx.x * 512 + threadIdx.x; e < N_EDGES; e += stride)
        atomicAdd(&h[dst[e] >> BKT_SHIFT], 1);
    __syncthreads();
    for (int i = threadIdx.x; i < NBK; i += 512) {
        int v = h[i];
        if (v) atomicAdd(&bhist[i], v);
    }
}

// ---------------- single-block scan of bucket histogram ----------------
__global__ __launch_bounds__(512) void scan_bhist_kernel(const int* __restrict__ bhist,
                                                         int* __restrict__ bbase,
                                                         int* __restrict__ bcursor) {
    __shared__ int s[512];
    int t = threadIdx.x;
    int v = (t < NBK) ? bhist[t] : 0;
    s[t] = v;
    __syncthreads();
    for (int off = 1; off < 512; off <<= 1) {
        int u = (t >= off) ? s[t - off] : 0;
        __syncthreads();
        s[t] += u;
        __syncthreads();
    }
    if (t < NBK) {
        int excl = s[t] - v;
        bbase[t] = excl;
        bcursor[t] = excl;
    }
    if (t == 0) bbase[NBK] = N_EDGES;
}

// ---------------- phase A: bin edges by 256-node bucket, coalesced runs ----------------
__global__ __launch_bounds__(512) void binA_kernel(const int* __restrict__ src,
                                                   const int* __restrict__ dst,
                                                   int* __restrict__ bcursor,
                                                   int2* __restrict__ csr_tmp) {
    __shared__ int2 staged[CHUNK];   // 32 KB
    __shared__ int delta[CHUNK];     // 16 KB
    __shared__ int hist[NBK];
    __shared__ int lcur[NBK];
    __shared__ int gdel[NBK];
    __shared__ int scan_s[512];
    int t = threadIdx.x;
    int e0 = blockIdx.x * CHUNK;
    int n = N_EDGES - e0; if (n > CHUNK) n = CHUNK;

    for (int i = t; i < NBK; i += 512) hist[i] = 0;
    __syncthreads();
    for (int i = t; i < n; i += 512) atomicAdd(&hist[dst[e0 + i] >> BKT_SHIFT], 1);
    __syncthreads();
    int v = (t < NBK) ? hist[t] : 0;
    scan_s[t] = v;
    __syncthreads();
    for (int off = 1; off < 512; off <<= 1) {
        int u = (t >= off) ? scan_s[t - off] : 0;
        __syncthreads();
        scan_s[t] += u;
        __syncthreads();
    }
    if (t < NBK) {
        int excl = scan_s[t] - v;
        lcur[t] = excl;
        int g = atomicAdd(&bcursor[t], v);  // reserve contiguous run in bucket region
        gdel[t] = g - excl;
    }
    __syncthreads();
    for (int i = t; i < n; i += 512) {
        int s = src[e0 + i];
        int d = dst[e0 + i];
        int bkt = d >> BKT_SHIFT;
        int slot = atomicAdd(&lcur[bkt], 1);
        staged[slot] = make_int2(s, d);
        delta[slot] = gdel[bkt];
    }
    __syncthreads();
    for (int p = t; p < n; p += 512) csr_tmp[delta[p] + p] = staged[p];
}

// ---------------- phase B: per-bucket hist/scan/offs/dinv + exact CSR ordering ----------------
__global__ __launch_bounds__(256) void binB_kernel(const int* __restrict__ bbase,
                                                   const int2* __restrict__ csr_tmp,
                                                   int* __restrict__ offs,
                                                   float* __restrict__ dinv,
                                                   int* __restrict__ csr) {
    __shared__ int src_s[BCAP];            // 24 KB
    __shared__ unsigned char dloc[BCAP];   // 6 KB
    __shared__ int out_s[BCAP];            // 24 KB
    __shared__ int lcnt[BKT_NODES];
    __shared__ int ss[BKT_NODES];
    __shared__ int lcur[BKT_NODES];
    int t = threadIdx.x;
    int node0 = blockIdx.x * BKT_NODES;
    int base = bbase[blockIdx.x];
    int cnt = bbase[blockIdx.x + 1] - base;
    lcnt[t] = 0;
    __syncthreads();
    bool fits = (cnt <= BCAP);
    if (fits) {
        for (int i = t; i < cnt; i += 256) {
            int2 e = csr_tmp[base + i];
            int dl = e.y - node0;
            src_s[i] = e.x;
            dloc[i] = (unsigned char)dl;
            atomicAdd(&lcnt[dl], 1);
        }
    } else {
        for (int i = t; i < cnt; i += 256) atomicAdd(&lcnt[csr_tmp[base + i].y - node0], 1);
    }
    __syncthreads();
    int v = lcnt[t];
    ss[t] = v;
    __syncthreads();
    for (int off = 1; off < 256; off <<= 1) {
        int u = (t >= off) ? ss[t - off] : 0;
        __syncthreads();
        ss[t] += u;
        __syncthreads();
    }
    int excl = ss[t] - v;
    lcur[t] = excl;
    int node = node0 + t;
    if (node < N_NODES) {
        offs[node] = base + excl;
        dinv[node] = rsqrtf((float)v + 1.0f);
    }
    if (blockIdx.x == NBK - 1 && t == 0) offs[N_NODES] = N_EDGES;
    __syncthreads();
    if (fits) {
        for (int i = t; i < cnt; i += 256) {
            int slot = atomicAdd(&lcur[dloc[i]], 1);
            out_s[slot] = src_s[i];
        }
        __syncthreads();
        for (int i = t; i < cnt; i += 256) csr[base + i] = out_s[i];
    } else {
        for (int i = t; i < cnt; i += 256) {
            int2 e = csr_tmp[base + i];
            int slot = atomicAdd(&lcur[e.y - node0], 1);
            csr[base + slot] = e.x;
        }
    }
}

// ---------------- prescale: Xs = X * dinv (row-wise) ----------------
__global__ __launch_bounds__(256) void prescale_kernel(const float* __restrict__ X,
                                                       const float* __restrict__ dinv,
                                                       float* __restrict__ Xs) {
    int i = blockIdx.x * 256 + threadIdx.x;  // float4 index
    if (i < N_NODES * 16) {
        float4 v = ((const float4*)X)[i];
        float d = dinv[i >> 4];
        float4 o = make_float4(v.x * d, v.y * d, v.z * d, v.w * d);
        ((float4*)Xs)[i] = o;
    }
}

// ---------------- pure gather: Agg[n] = dinv[n] * (Xs[n] + sum_{s in in(n)} Xs[s]) ----------------
__global__ __launch_bounds__(256) void gather_kernel(
    const float* __restrict__ Xs, const float* __restrict__ dinv,
    const int* __restrict__ offs, const int* __restrict__ csr,
    float* __restrict__ Agg, int n_waves) {
    int lane = threadIdx.x & 63;
    int wid = (blockIdx.x * blockDim.x + threadIdx.x) >> 6;
    int sub = lane >> 4;       // 0..3: edge slot within 4-group
    int l16 = lane & 15;       // 4-channel group
    const float4* Xv = (const float4*)Xs;
    float4* Av = (float4*)Agg;

    for (int node = wid; node < N_NODES; node += n_waves) {
        float di = dinv[node];
        int beg = offs[node], end = offs[node + 1];
        float4 acc;
        if (sub == 0) {
            acc = Xv[node * 16 + l16];          // own (pre-scaled) row
        } else {
            acc = make_float4(0.f, 0.f, 0.f, 0.f);
        }
        // dual-stream edge loop: 8 edges/iteration, two independent 1KB row
        // loads in flight + 2 csr prefetches (depth-2 per stream)
        int i = beg + sub;                       // stream0: i, i+8, ...  stream1: i+4, i+12, ...
        int sA0 = (i      < end) ? csr[i]      : 0;
        int sA1 = (i + 4  < end) ? csr[i + 4]  : 0;
        int sB0 = (i + 8  < end) ? csr[i + 8]  : 0;
        int sB1 = (i + 12 < end) ? csr[i + 12] : 0;
        float4 rA0 = Xv[(size_t)sA0 * 16 + l16];
        float4 rA1 = Xv[(size_t)sA1 * 16 + l16];
        while (i < end) {
            float4 rB0 = Xv[(size_t)sB0 * 16 + l16];
            float4 rB1 = Xv[(size_t)sB1 * 16 + l16];
            int sC0 = (i + 16 < end) ? csr[i + 16] : 0;
            int sC1 = (i + 20 < end) ? csr[i + 20] : 0;
            float m1 = (i + 4 < end) ? 1.0f : 0.0f;   // stream0 add is covered by loop cond
            acc.x += rA0.x; acc.y += rA0.y; acc.z += rA0.z; acc.w += rA0.w;
            acc.x = fmaf(rA1.x, m1, acc.x);
            acc.y = fmaf(rA1.y, m1, acc.y);
            acc.z = fmaf(rA1.z, m1, acc.z);
            acc.w = fmaf(rA1.w, m1, acc.w);
            rA0 = rB0; rA1 = rB1;
            sB0 = sC0; sB1 = sC1;
            i += 8;
        }
        // reduce across the 4 subs
        acc.x += __shfl_xor(acc.x, 16, 64); acc.y += __shfl_xor(acc.y, 16, 64);
        acc.z += __shfl_xor(acc.z, 16, 64); acc.w += __shfl_xor(acc.w, 16, 64);
        acc.x += __shfl_xor(acc.x, 32, 64); acc.y += __shfl_xor(acc.y, 32, 64);
        acc.z += __shfl_xor(acc.z, 32, 64); acc.w += __shfl_xor(acc.w, 32, 64);
        if (sub == 0) {
            acc.x *= di; acc.y *= di; acc.z *= di; acc.w *= di;
            Av[node * 16 + l16] = acc;
        }
    }
}

// ---------------- MFMA dense epilogue: out = (A @ W + b) [* dinv] ----------------
// f16x2 split precision: A = Ah + Al, W = Wh + Wl (each f16); fp32-accumulated
// mfma products hh + hl + lh + ll reconstruct fp32-quality A@W.
// mfma_f32_16x16x32_f16 layouts: A row = lane&15; B col = lane&15;
// D: col = lane&15, row = (lane>>4)*4 + reg. k-position map is a free bijection
// as long as A and B fragments use the same one (k = 32c + 8*(lane>>4) + j).
__global__ __launch_bounds__(256) void mlp_mfma_kernel(
    const float* __restrict__ A, const float* __restrict__ W,
    const float* __restrict__ b, const float* __restrict__ dinv,
    float* __restrict__ out, int prescale_out) {
    int l = threadIdx.x & 63;
    int wv = threadIdx.x >> 6;
    int m = l & 15;            // A row / B col / D col
    int g = l >> 4;            // k-group
    int node0 = blockIdx.x * 64 + wv * 16;
    if (node0 >= N_NODES) return;

    // ---- W fragments (hoisted; ~64 VGPRs) ----
    half8 wh[4][2], wl[4][2];
#pragma unroll
    for (int t = 0; t < 4; t++) {
#pragma unroll
        for (int c = 0; c < 2; c++) {
#pragma unroll
            for (int j = 0; j < 8; j++) {
                float w = W[(32 * c + 8 * g + j) * 64 + 16 * t + m];
                _Float16 h = (_Float16)w;
                wh[t][c][j] = h;
                wl[t][c][j] = (_Float16)(w - (float)h);
            }
        }
    }
    float bfrag[4];
#pragma unroll
    for (int t = 0; t < 4; t++) bfrag[t] = b[16 * t + m];

    // ---- A fragments (one 16-node tile per wave) ----
    const float4* Avv = (const float4*)A;
    int row = node0 + m;
    int rcl = (row < N_NODES) ? row : (N_NODES - 1);   // tail-safe (dup rows, stores guarded)
    half8 ah[2], al[2];
#pragma unroll
    for (int c = 0; c < 2; c++) {
        float4 a0 = Avv[rcl * 16 + 8 * c + 2 * g];
        float4 a1 = Avv[rcl * 16 + 8 * c + 2 * g + 1];
        float av[8] = {a0.x, a0.y, a0.z, a0.w, a1.x, a1.y, a1.z, a1.w};
#pragma unroll
        for (int j = 0; j < 8; j++) {
            _Float16 h = (_Float16)av[j];
            ah[c][j] = h;
            al[c][j] = (_Float16)(av[j] - (float)h);
        }
    }

    floatx4 acc[4];
#pragma unroll
    for (int t = 0; t < 4; t++) { acc[t][0] = 0.f; acc[t][1] = 0.f; acc[t][2] = 0.f; acc[t][3] = 0.f; }

#pragma unroll
    for (int c = 0; c < 2; c++) {
#pragma unroll
        for (int t = 0; t < 4; t++) {
            acc[t] = __builtin_amdgcn_mfma_f32_16x16x32_f16(ah[c], wh[t][c], acc[t], 0, 0, 0);
            acc[t] = __builtin_amdgcn_mfma_f32_16x16x32_f16(ah[c], wl[t][c], acc[t], 0, 0, 0);
            acc[t] = __builtin_amdgcn_mfma_f32_16x16x32_f16(al[c], wh[t][c], acc[t], 0, 0, 0);
            acc[t] = __builtin_amdgcn_mfma_f32_16x16x32_f16(al[c], wl[t][c], acc[t], 0, 0, 0);
        }
    }

    float dv[4];
#pragma unroll
    for (int r = 0; r < 4; r++) {
        int node = node0 + 4 * g + r;
        dv[r] = (node < N_NODES) ? dinv[node] : 0.f;
    }
#pragma unroll
    for (int t = 0; t < 4; t++) {
#pragma unroll
        for (int r = 0; r < 4; r++) {
            int node = node0 + 4 * g + r;
            if (node < N_NODES) {
                float v = acc[t][r] + bfrag[t];
                if (prescale_out) v *= dv[r];
                out[(size_t)node * 64 + 16 * t + m] = v;
            }
        }
    }
}

extern "C" void kernel_launch(void* const* d_in, const int* in_sizes, int n_in,
                              void* d_out, int out_size, void* d_ws, size_t ws_size,
                              hipStream_t stream) {
    const float* emb = (const float*)d_in[0];
    const int* edge  = (const int*)d_in[1];
    const float* W1 = (const float*)d_in[2];
    const float* b1 = (const float*)d_in[3];
    const float* W2 = (const float*)d_in[4];
    const float* b2 = (const float*)d_in[5];
    const float* W3 = (const float*)d_in[6];
    const float* b3 = (const float*)d_in[7];
    float* out = (float*)d_out;

    const int* src = edge;
    const int* dst = edge + N_EDGES;

    char* ws = (char*)d_ws;
    size_t off = 0;
    int* bhist = (int*)(ws + off);      off += 2048;
    int* bbase = (int*)(ws + off);      off += 2048;     // NBK+1
    int* bcursor = (int*)(ws + off);    off += 2048;
    int* offs = (int*)(ws + off);       off += 400128;   // N_NODES+1
    float* dinv = (float*)(ws + off);   off += 400128;
    int2* csr_tmp = (int2*)(ws + off);  off += 12800128;
    int* csr = (int*)(ws + off);        off += 6400128;
    float* Xa = (float*)(ws + off);     off += 25600000;
    float* Xb = (float*)(ws + off);     // 25.6 MB

    // ---- CSR build (shared by all 3 layers) ----
    hipMemsetAsync(bhist, 0, NBK * sizeof(int), stream);
    bhist_kernel<<<64, 512, 0, stream>>>(dst, bhist);
    scan_bhist_kernel<<<1, 512, 0, stream>>>(bhist, bbase, bcursor);
    binA_kernel<<<NCHUNKS, 512, 0, stream>>>(src, dst, bcursor, csr_tmp);
    binB_kernel<<<NBK, 256, 0, stream>>>(bbase, csr_tmp, offs, dinv, csr);

    // Xs1 = emb * dinv  -> Xa
    prescale_kernel<<<(N_NODES * 16 + 255) / 256, 256, 0, stream>>>(emb, dinv, Xa);

    const int GBLOCKS = 2048;                 // 8192 waves
    const int n_waves = GBLOCKS * 256 / 64;
    const int MBLOCKS = (N_NODES + 63) / 64;  // 1563

    // layer 1
    gather_kernel<<<GBLOCKS, 256, 0, stream>>>(Xa, dinv, offs, csr, Xb, n_waves);
    mlp_mfma_kernel<<<MBLOCKS, 256, 0, stream>>>(Xb, W1, b1, dinv, Xa, 1);
    // layer 2
    gather_kernel<<<GBLOCKS, 256, 0, stream>>>(Xa, dinv, offs, csr, Xb, n_waves);
    mlp_mfma_kernel<<<MBLOCKS, 256, 0, stream>>>(Xb, W2, b2, dinv, Xa, 1);
    // layer 3 (no prescale on final output)
    gather_kernel<<<GBLOCKS, 256, 0, stream>>>(Xa, dinv, offs, csr, Xb, n_waves);
    mlp_mfma_kernel<<<MBLOCKS, 256, 0, stream>>>(Xb, W3, b3, dinv, out, 0);
}